// Round 11
// baseline (984.200 us; speedup 1.0000x reference)
//
#include <hip/hip_runtime.h>
#include <math.h>

#define TB    720
#define NI    16
#define NH    128
#define NG    512
#define PRED  96
#define CHUNK 90          // 720 = 8 * 90

typedef _Float16 h2    __attribute__((ext_vector_type(2)));
typedef _Float16 f16x4 __attribute__((ext_vector_type(4)));
typedef _Float16 f16x8 __attribute__((ext_vector_type(8)));
typedef float    f32x4 __attribute__((ext_vector_type(4)));

__device__ __forceinline__ float rcpf_(float v) {
#if __has_builtin(__builtin_amdgcn_rcpf)
    return __builtin_amdgcn_rcpf(v);
#else
    return 1.0f / v;
#endif
}
__device__ __forceinline__ float sigf(float v)   { return rcpf_(1.0f + __expf(-v)); }
__device__ __forceinline__ float tanhf_(float v) { return 1.0f - 2.0f * rcpf_(1.0f + __expf(2.0f * v)); }

__device__ __forceinline__ unsigned int packf16(float a, float b) {
    h2 p; p.x = (_Float16)a; p.y = (_Float16)b;
    return __builtin_bit_cast(unsigned int, p);
}
__device__ __forceinline__ float2 unpackf16(unsigned int u) {
    h2 p = __builtin_bit_cast(h2, u);
    return make_float2((float)p.x, (float)p.y);
}
__device__ __forceinline__ float fdot2f(unsigned int a, unsigned int b, float c) {
#if __has_builtin(__builtin_amdgcn_fdot2)
    return __builtin_amdgcn_fdot2(__builtin_bit_cast(h2, a), __builtin_bit_cast(h2, b), c, false);
#else
    h2 x = __builtin_bit_cast(h2, a), y = __builtin_bit_cast(h2, b);
    return c + (float)x.x * (float)y.x + (float)x.y * (float)y.y;
#endif
}

// A/B frag split-half k layout (verified R9/R10): elem j -> k = (j>>2)*16 + lk*4 + (j&3)
__device__ __forceinline__ f16x8 mk8(const float* p) {
    f16x8 v;
    v[0] = (_Float16)p[0];  v[1] = (_Float16)p[1];  v[2] = (_Float16)p[2];  v[3] = (_Float16)p[3];
    v[4] = (_Float16)p[16]; v[5] = (_Float16)p[17]; v[6] = (_Float16)p[18]; v[7] = (_Float16)p[19];
    return v;
}
__device__ __forceinline__ f32x4 MFMA(f16x8 a, f16x8 b, f32x4 c) {
    return __builtin_amdgcn_mfma_f32_16x16x32_f16(a, b, c, 0, 0, 0);
}
// block LLVM from hoisting loop-invariant LDS reads (hoist->spill hazard, R10-proven)
__device__ __forceinline__ int opaque(int v) { asm volatile("" : "+v"(v)); return v; }

// ---------------- encoder (MFMA, 512thr, zero global ops in step loop) ----------------
// grid 32 = (batch/16) x dir; block 512 = 8 waves; wave owns 4 m-tiles.
// gates'[512][16b] = W'[512][K=32pad+128] @ [x|h]^T per step; R=4d+g row perm.
// h LDS layout = B-frag order: frag (KS,lk) of batch b at byte b*256+KS*64+lk*16
// (^ (b&7)<<4), one aligned b128 per frag. x staged per 90-step chunk as f16.
// Bias enters as C-init (b128 broadcast from LDS).
__global__ __launch_bounds__(512, 1)
void enc_kernel(const float* __restrict__ x,
                const float* __restrict__ Wih_f, const float* __restrict__ Whh_f, const float* __restrict__ b_f,
                const float* __restrict__ Wih_b, const float* __restrict__ Whh_b, const float* __restrict__ b_b,
                float* __restrict__ st)   // st[b][dir][{h,c}][NH]
{
    __shared__ _Float16 hbuf0[16 * NH];        // 4KB
    __shared__ _Float16 hbuf1[16 * NH];        // 4KB
    __shared__ unsigned int wxl[32 * 128];     // Wih' [mt][lk][lr] f16x4: 16KB
    __shared__ float blq[NG];                  // bias, perm order: 2KB
    __shared__ unsigned int xsh[CHUNK * 128];  // x f16 [si][lk][lr]: 46KB

    const int blk = blockIdx.x;
    const int dir = blk & 1;
    const int b0  = (blk >> 1) << 4;
    const int t   = threadIdx.x;
    const int wv  = t >> 6;
    const int l   = t & 63;
    const int lr  = l & 15;
    const int lk  = l >> 4;

    const float* Wih = dir ? Wih_b : Wih_f;
    const float* Whh = dir ? Whh_b : Whh_f;
    const float* bv  = dir ? b_b   : b_f;

    // stage Wih' (perm rows, [mt][lk][lr] f16x4) + bias (perm order, f32)
    {
        const int o = t, R = (o & 127) * 4 + (o >> 7);
        const int mt = R >> 4, lrW = R & 15;
        const float* src = Wih + (size_t)o * NI;
#pragma unroll
        for (int kk = 0; kk < 4; ++kk) {
            wxl[mt * 128 + kk * 32 + lrW * 2]     = packf16(src[kk * 4],     src[kk * 4 + 1]);
            wxl[mt * 128 + kk * 32 + lrW * 2 + 1] = packf16(src[kk * 4 + 2], src[kk * 4 + 3]);
        }
        blq[R] = bv[o];
    }

    // ---- static A-h frags: 16 named f16x8 ----
    const int mt0 = wv * 4, mt1 = wv * 4 + 1, mt2 = wv * 4 + 2, mt3 = wv * 4 + 3;
    const int R0 = mt0 * 16 + lr, R1 = mt1 * 16 + lr, R2 = mt2 * 16 + lr, R3 = mt3 * 16 + lr;
    const int or0 = (R0 & 3) * 128 + (R0 >> 2);
    const int or1 = (R1 & 3) * 128 + (R1 >> 2);
    const int or2 = (R2 & 3) * 128 + (R2 >> 2);
    const int or3 = (R3 & 3) * 128 + (R3 >> 2);
    const float* p0 = Whh + (size_t)or0 * NH + lk * 4;
    const float* p1 = Whh + (size_t)or1 * NH + lk * 4;
    const float* p2 = Whh + (size_t)or2 * NH + lk * 4;
    const float* p3 = Whh + (size_t)or3 * NH + lk * 4;
    f16x8 w0_0 = mk8(p0), w0_1 = mk8(p0 + 32), w0_2 = mk8(p0 + 64), w0_3 = mk8(p0 + 96);
    f16x8 w1_0 = mk8(p1), w1_1 = mk8(p1 + 32), w1_2 = mk8(p1 + 64), w1_3 = mk8(p1 + 96);
    f16x8 w2_0 = mk8(p2), w2_1 = mk8(p2 + 32), w2_2 = mk8(p2 + 64), w2_3 = mk8(p2 + 96);
    f16x8 w3_0 = mk8(p3), w3_1 = mk8(p3 + 32), w3_2 = mk8(p3 + 64), w3_3 = mk8(p3 + 96);

    const int d0 = mt0 * 4 + lk, d1 = mt1 * 4 + lk, d2 = mt2 * 4 + lk, d3 = mt3 * 4 + lk;

    // zero h buffer 0
    ((unsigned int*)hbuf0)[t] = 0u;
    ((unsigned int*)hbuf0)[t + 512] = 0u;
    float cs0 = 0.f, cs1 = 0.f, cs2 = 0.f, cs3 = 0.f;

    const int swz = (lr & 7) << 4;
    // loop-invariant offsets
    const int hro0 = (lr * 256 + 0 * 64 + lk * 16) ^ swz;
    const int hro1 = (lr * 256 + 1 * 64 + lk * 16) ^ swz;
    const int hro2 = (lr * 256 + 2 * 64 + lk * 16) ^ swz;
    const int hro3 = (lr * 256 + 3 * 64 + lk * 16) ^ swz;
    const int axo0 = mt0 * 512 + lk * 128 + lr * 8;    // bytes into wxl
    const int axo1 = mt1 * 512 + lk * 128 + lr * 8;
    const int axo2 = mt2 * 512 + lk * 128 + lr * 8;
    const int axo3 = mt3 * 512 + lk * 128 + lr * 8;
    const int bqo0 = mt0 * 16 + lk * 4;                // f32 idx into blq
    const int bqo1 = mt1 * 16 + lk * 4;
    const int bqo2 = mt2 * 16 + lk * 4;
    const int bqo3 = mt3 * 16 + lk * 4;
    // cell h-write byte offsets (k=dJ): KS=k>>5, rem=k&31, j=(rem>>4)*4+(rem&3), lkW=(rem&15)>>2
#define CWB(D) (((lr * 256) + ((D) >> 5) * 64 + ((((D) & 15)) >> 2) * 16 + (((((D) & 31) >> 4) * 4 + ((D) & 3)) * 2)) ^ swz)
    const int cwb0 = CWB(d0), cwb1 = CWB(d1), cwb2 = CWB(d2), cwb3 = CWB(d3);
#undef CWB
    const int xoff = lk * 128 + lr * 8;                // bytes into xsh row
    __syncthreads();

#define MKAX(DST, OFF) { \
    f16x4 lo_ = *(const f16x4*)((const char*)wxl + opaque(OFF)); \
    DST[0] = lo_[0]; DST[1] = lo_[1]; DST[2] = lo_[2]; DST[3] = lo_[3]; \
    DST[4] = (_Float16)0.f; DST[5] = (_Float16)0.f; DST[6] = (_Float16)0.f; DST[7] = (_Float16)0.f; }

#define CELL(J, HW) { \
    float ci_ = sigf(C##J[0]), cf_ = sigf(C##J[1]); \
    float cg_ = tanhf_(C##J[2]), co_ = sigf(C##J[3]); \
    cs##J = cf_ * cs##J + ci_ * cg_; \
    float hv_ = co_ * tanhf_(cs##J); \
    *(_Float16*)((char*)(HW) + cwb##J) = (_Float16)hv_; }

#define STEP(HR, HW, SI) { \
    const char* hrb_ = (const char*)(HR); \
    f16x8 bh0 = *(const f16x8*)(hrb_ + hro0); \
    f16x8 bh1 = *(const f16x8*)(hrb_ + hro1); \
    f16x8 bh2 = *(const f16x8*)(hrb_ + hro2); \
    f16x8 bh3 = *(const f16x8*)(hrb_ + hro3); \
    f16x4 xlo_ = *(const f16x4*)((const char*)xsh + (SI) * 512 + xoff); \
    f16x8 bx; \
    bx[0] = xlo_[0]; bx[1] = xlo_[1]; bx[2] = xlo_[2]; bx[3] = xlo_[3]; \
    bx[4] = (_Float16)0.f; bx[5] = (_Float16)0.f; bx[6] = (_Float16)0.f; bx[7] = (_Float16)0.f; \
    f16x8 ax0, ax1, ax2, ax3; \
    MKAX(ax0, axo0) MKAX(ax1, axo1) MKAX(ax2, axo2) MKAX(ax3, axo3) \
    f32x4 C0 = *(const f32x4*)(blq + opaque(bqo0)); \
    f32x4 C1 = *(const f32x4*)(blq + opaque(bqo1)); \
    f32x4 C2 = *(const f32x4*)(blq + opaque(bqo2)); \
    f32x4 C3 = *(const f32x4*)(blq + opaque(bqo3)); \
    C0 = MFMA(ax0, bx, C0); C1 = MFMA(ax1, bx, C1); \
    C2 = MFMA(ax2, bx, C2); C3 = MFMA(ax3, bx, C3); \
    C0 = MFMA(w0_0, bh0, C0); C1 = MFMA(w1_0, bh0, C1); \
    C2 = MFMA(w2_0, bh0, C2); C3 = MFMA(w3_0, bh0, C3); \
    C0 = MFMA(w0_1, bh1, C0); C1 = MFMA(w1_1, bh1, C1); \
    C2 = MFMA(w2_1, bh1, C2); C3 = MFMA(w3_1, bh1, C3); \
    C0 = MFMA(w0_2, bh2, C0); C1 = MFMA(w1_2, bh2, C1); \
    C2 = MFMA(w2_2, bh2, C2); C3 = MFMA(w3_2, bh2, C3); \
    C0 = MFMA(w0_3, bh3, C0); C1 = MFMA(w1_3, bh3, C1); \
    C2 = MFMA(w2_3, bh3, C2); C3 = MFMA(w3_3, bh3, C3); \
    CELL(0, HW) CELL(1, HW) CELL(2, HW) CELL(3, HW) \
    __syncthreads(); }

    for (int c = 0; c < 8; ++c) {
        // ---- stage x chunk -> f16 LDS [si][lk][lr] (only global reads outside steps)
        {
            const int c0 = c * CHUNK;
            for (int i = t; i < 16 * CHUNK * 8; i += 512) {
                const int br  = i / (CHUNK * 8);
                const int rem = i - br * (CHUNK * 8);
                const int ti  = rem >> 3;
                const int dw  = rem & 7;
                const int s_  = c0 + ti;
                const int tt  = dir ? (TB - 1 - s_) : s_;
                float2 v = *(const float2*)(x + ((size_t)(b0 + br) * TB + tt) * NI + dw * 2);
                xsh[ti * 128 + (dw >> 1) * 32 + br * 2 + (dw & 1)] = packf16(v.x, v.y);
            }
        }
        __syncthreads();
        for (int si2 = 0; si2 < CHUNK / 2; ++si2) {
            STEP(hbuf0, hbuf1, si2 * 2)        // even step
            STEP(hbuf1, hbuf0, si2 * 2 + 1)    // odd step
        }
    }
#undef STEP
#undef CELL
#undef MKAX

    // final states: h in hbuf0 (720 even), c in regs
    {
        const size_t base = ((size_t)(b0 + lr) * 2 + dir) * 2 * NH;
#define FIN(J) { \
        float hv_ = (float)*(const _Float16*)((const char*)hbuf0 + cwb##J); \
        st[base + d##J] = hv_; st[base + NH + d##J] = cs##J; }
        FIN(0) FIN(1) FIN(2) FIN(3)
#undef FIN
    }
}

// named-var repetition macros (arrays get scratch-demoted: R4/R6 evidence)
#define R8(F)  F(0)F(1)F(2)F(3)F(4)F(5)F(6)F(7)
#define R36_(F) F(8)F(9)F(10)F(11)F(12)F(13)F(14)F(15)F(16)F(17)F(18)F(19)F(20)F(21)F(22)F(23)F(24)F(25)F(26)F(27)F(28)F(29)F(30)F(31)F(32)F(33)F(34)F(35)
#define R36(F) R8(F) R36_(F)
#define R64(F) R36(F) F(36)F(37)F(38)F(39)F(40)F(41)F(42)F(43)F(44)F(45)F(46)F(47)F(48)F(49)F(50)F(51)F(52)F(53)F(54)F(55)F(56)F(57)F(58)F(59)F(60)F(61)F(62)F(63)

#define QD(Q,i0,i1,i2,i3) { a0 = fdot2f((Q).x, w##i0, a0); a1 = fdot2f((Q).y, w##i1, a1); \
                            a2 = fdot2f((Q).z, w##i2, a2); a3 = fdot2f((Q).w, w##i3, a3); }
#define QDU(Q,i0,i1,i2,i3) { a0 = fdot2f((Q).x, u##i0, a0); a1 = fdot2f((Q).y, u##i1, a1); \
                             a2 = fdot2f((Q).z, u##i2, a2); a3 = fdot2f((Q).w, u##i3, a3); }

// ---------------- decoder (R7 structure; Wlin/blin/out all LDS-resident) ----------------
__global__ __launch_bounds__(1024, 1)
void dec_kernel(const float* __restrict__ x,
                const float* __restrict__ Wih_f, const float* __restrict__ Whh_f, const float* __restrict__ b_f,
                const float* __restrict__ Wih_b, const float* __restrict__ Whh_b, const float* __restrict__ b_b,
                const float* __restrict__ Wlin, const float* __restrict__ blin,
                const float* __restrict__ st, float* __restrict__ out)
{
    __shared__ unsigned int hFh[NH / 2], hBh[NH / 2];
    __shared__ unsigned int inpH[NI / 2];
    __shared__ float g[1024];
    __shared__ float prt[NG];
    __shared__ float wlin_s[16 * 256];   // 16KB
    __shared__ float blin_s[16];
    __shared__ float obuf[PRED * 16];    // 6KB output buffer, flushed at end

    const int b    = blockIdx.x;
    const int t    = threadIdx.x;
    const int cell = t >> 9;
    const int r    = t & 511;

    const float* Wih = cell ? Wih_b : Wih_f;
    const float* Whh = cell ? Whh_b : Whh_f;
    const float* bv  = cell ? b_b   : b_f;

    // stage Wlin + blin (removes all in-loop global reads)
    for (int i = t; i < 16 * 256; i += 1024) wlin_s[i] = Wlin[i];
    if (t < 16) blin_s[t] = blin[t];

#define DW(K) unsigned int w##K;
    R64(DW)
#undef DW
#define DU(K) unsigned int u##K;
    R8(DU)
#undef DU
    {
        const float* xr = Wih + r * NI;
        const float* hr = Whh + r * NH;
#define LU(K) u##K = packf16(xr[2*(K)], xr[2*(K)+1]);
        R8(LU)
#undef LU
#define LH(K) w##K = packf16(hr[2*(K)], hr[2*(K)+1]);
        R64(LH)
#undef LH
    }
    const float bias = bv[r];

    float cc = 0.0f;
    if (t < 64) {
        const float* sh = st + ((b * 2 + 0) * 2 + 0) * NH;
        hFh[t] = packf16(sh[2 * t], sh[2 * t + 1]);
    } else if (t < 128) {
        const float* sh = st + ((b * 2 + 1) * 2 + 0) * NH;
        hBh[t - 64] = packf16(sh[2 * (t - 64)], sh[2 * (t - 64) + 1]);
    }
    if (t < NH) cc = st[((b * 2 + 0) * 2 + 1) * NH + t];
    else if (t >= 512 && t < 512 + NH) cc = st[((b * 2 + 1) * 2 + 1) * NH + (t - 512)];
    if (t < 8) {
        float2 v = ((const float2*)(x + (size_t)b * TB * NI + (TB - 1) * NI))[t];
        inpH[t] = packf16(v.x, v.y);
    }
    __syncthreads();

    for (int s = 0; s < PRED; ++s) {
        float a0 = bias, a1 = 0.f, a2 = 0.f, a3 = 0.f;
        uint4 q;
        {
            const uint4* xv = (const uint4*)inpH;
            q = xv[0]; QDU(q, 0, 1, 2, 3)
            q = xv[1]; QDU(q, 4, 5, 6, 7)
        }
        const uint4* hv = cell ? (const uint4*)hBh : (const uint4*)hFh;
        q = hv[0];  QD(q, 0, 1, 2, 3)
        q = hv[1];  QD(q, 4, 5, 6, 7)
        q = hv[2];  QD(q, 8, 9, 10, 11)
        q = hv[3];  QD(q, 12, 13, 14, 15)
        q = hv[4];  QD(q, 16, 17, 18, 19)
        q = hv[5];  QD(q, 20, 21, 22, 23)
        q = hv[6];  QD(q, 24, 25, 26, 27)
        q = hv[7];  QD(q, 28, 29, 30, 31)
        q = hv[8];  QD(q, 32, 33, 34, 35)
        q = hv[9];  QD(q, 36, 37, 38, 39)
        q = hv[10]; QD(q, 40, 41, 42, 43)
        q = hv[11]; QD(q, 44, 45, 46, 47)
        q = hv[12]; QD(q, 48, 49, 50, 51)
        q = hv[13]; QD(q, 52, 53, 54, 55)
        q = hv[14]; QD(q, 56, 57, 58, 59)
        q = hv[15]; QD(q, 60, 61, 62, 63)
        g[t] = (a0 + a1) + (a2 + a3);
        __syncthreads();
        if ((t < NH) || (t >= 512 && t < 512 + NH)) {
            float gi = g[t], gf = g[t + NH], gg = g[t + 2 * NH], go = g[t + 3 * NH];
            cc = sigf(gf) * cc + sigf(gi) * tanhf_(gg);
            float h = sigf(go) * tanhf_(cc);
            if (t < NH) ((_Float16*)hFh)[t] = (_Float16)h;
            else        ((_Float16*)hBh)[t - 512] = (_Float16)h;
        }
        __syncthreads();
        if (t < NG) {
            const int j = t >> 5, ch = t & 31;
            const unsigned int* hsrc = (ch < 16) ? (hFh + ch * 4) : (hBh + (ch - 16) * 4);
            const float* wl = wlin_s + j * 256 + ch * 8;
            float2 v0 = unpackf16(hsrc[0]);
            float2 v1 = unpackf16(hsrc[1]);
            float2 v2 = unpackf16(hsrc[2]);
            float2 v3 = unpackf16(hsrc[3]);
            prt[t] = v0.x * wl[0] + v0.y * wl[1] + v1.x * wl[2] + v1.y * wl[3]
                   + v2.x * wl[4] + v2.y * wl[5] + v3.x * wl[6] + v3.y * wl[7];
        }
        __syncthreads();
        if (t < NI) {
            float o = blin_s[t];
#pragma unroll
            for (int c2 = 0; c2 < 32; ++c2) o += prt[t * 32 + c2];
            obuf[s * NI + t] = o;
            ((_Float16*)inpH)[t] = (_Float16)o;
        }
        __syncthreads();
    }

    // flush outputs (coalesced float4)
    {
        float4* dst = (float4*)(out + (size_t)b * PRED * NI);
        const float4* src = (const float4*)obuf;
        for (int i = t; i < PRED * NI / 4; i += 1024) dst[i] = src[i];
    }
}

extern "C" void kernel_launch(void* const* d_in, const int* in_sizes, int n_in,
                              void* d_out, int out_size, void* d_ws, size_t ws_size,
                              hipStream_t stream)
{
    const float* x      = (const float*)d_in[0];
    const float* eWih_f = (const float*)d_in[1];
    const float* eWhh_f = (const float*)d_in[2];
    const float* eb_f   = (const float*)d_in[3];
    const float* eWih_b = (const float*)d_in[4];
    const float* eWhh_b = (const float*)d_in[5];
    const float* eb_b   = (const float*)d_in[6];
    const float* dWih_f = (const float*)d_in[7];
    const float* dWhh_f = (const float*)d_in[8];
    const float* db_f   = (const float*)d_in[9];
    const float* dWih_b = (const float*)d_in[10];
    const float* dWhh_b = (const float*)d_in[11];
    const float* db_b   = (const float*)d_in[12];
    const float* Wlin   = (const float*)d_in[13];
    const float* blin   = (const float*)d_in[14];

    float* st = (float*)d_ws;  // 256*2*2*128 f32 encoder final states

    enc_kernel<<<32, 512, 0, stream>>>(x, eWih_f, eWhh_f, eb_f, eWih_b, eWhh_b, eb_b, st);
    dec_kernel<<<256, 1024, 0, stream>>>(x, dWih_f, dWhh_f, db_f, dWih_b, dWhh_b, db_b,
                                         Wlin, blin, st, (float*)d_out);
}

// Round 12
// 837.295 us; speedup vs baseline: 1.1755x; 1.1755x over previous
//
#include <hip/hip_runtime.h>
#include <math.h>

#define TB    720
#define NI    16
#define NH    128
#define NG    512
#define PRED  96
#define CHUNK 90          // 720 = 8 * 90

typedef _Float16 h2    __attribute__((ext_vector_type(2)));
typedef _Float16 f16x4 __attribute__((ext_vector_type(4)));
typedef _Float16 f16x8 __attribute__((ext_vector_type(8)));
typedef float    f32x4 __attribute__((ext_vector_type(4)));

__device__ __forceinline__ float rcpf_(float v) {
#if __has_builtin(__builtin_amdgcn_rcpf)
    return __builtin_amdgcn_rcpf(v);
#else
    return 1.0f / v;
#endif
}
__device__ __forceinline__ float sigf(float v)   { return rcpf_(1.0f + __expf(-v)); }
__device__ __forceinline__ float tanhf_(float v) { return 1.0f - 2.0f * rcpf_(1.0f + __expf(2.0f * v)); }

__device__ __forceinline__ unsigned int packf16(float a, float b) {
    h2 p; p.x = (_Float16)a; p.y = (_Float16)b;
    return __builtin_bit_cast(unsigned int, p);
}
__device__ __forceinline__ float2 unpackf16(unsigned int u) {
    h2 p = __builtin_bit_cast(h2, u);
    return make_float2((float)p.x, (float)p.y);
}
__device__ __forceinline__ float fdot2f(unsigned int a, unsigned int b, float c) {
#if __has_builtin(__builtin_amdgcn_fdot2)
    return __builtin_amdgcn_fdot2(__builtin_bit_cast(h2, a), __builtin_bit_cast(h2, b), c, false);
#else
    h2 x = __builtin_bit_cast(h2, a), y = __builtin_bit_cast(h2, b);
    return c + (float)x.x * (float)y.x + (float)x.y * (float)y.y;
#endif
}

// A/B frag split-half k layout (verified R9-R11): elem j -> k = (j>>2)*16 + lk*4 + (j&3)
__device__ __forceinline__ f16x8 mk8(const float* p) {
    f16x8 v;
    v[0] = (_Float16)p[0];  v[1] = (_Float16)p[1];  v[2] = (_Float16)p[2];  v[3] = (_Float16)p[3];
    v[4] = (_Float16)p[16]; v[5] = (_Float16)p[17]; v[6] = (_Float16)p[18]; v[7] = (_Float16)p[19];
    return v;
}
__device__ __forceinline__ f32x4 MFMA(f16x8 a, f16x8 b, f32x4 c) {
    return __builtin_amdgcn_mfma_f32_16x16x32_f16(a, b, c, 0, 0, 0);
}

// ---------------- encoder (MFMA, 512thr, 5 LDS reads/thread/step) ----------------
// grid 32 = (batch/16) x dir; block 512 = 8 waves; wave owns 4 m-tiles.
// gates'[512][16b] = W'[512][K=32pad+128] @ [x;1|h]^T; R=4d+g row perm.
// ALL weights static in VGPR: 16 wh frags (64 regs) + 4 ax frags (16 regs,
// bias embedded at k=16 via ones-column: bx[4]=1 for lk==0). R11 was
// LDS-issue-bound at 13 reads/thread/step (ax+bias from LDS); now 5.
__global__ __launch_bounds__(512, 1)
void enc_kernel(const float* __restrict__ x,
                const float* __restrict__ Wih_f, const float* __restrict__ Whh_f, const float* __restrict__ b_f,
                const float* __restrict__ Wih_b, const float* __restrict__ Whh_b, const float* __restrict__ b_b,
                float* __restrict__ st)   // st[b][dir][{h,c}][NH]
{
    __shared__ _Float16 hbuf0[16 * NH];        // 4KB, B-frag order (R11 layout)
    __shared__ _Float16 hbuf1[16 * NH];        // 4KB
    __shared__ unsigned int xsh[CHUNK * 128];  // x f16 [si][lk][lr]: 46KB

    const int blk = blockIdx.x;
    const int dir = blk & 1;
    const int b0  = (blk >> 1) << 4;
    const int t   = threadIdx.x;
    const int wv  = t >> 6;
    const int l   = t & 63;
    const int lr  = l & 15;
    const int lk  = l >> 4;

    const float* Wih = dir ? Wih_b : Wih_f;
    const float* Whh = dir ? Whh_b : Whh_f;
    const float* bv  = dir ? b_b   : b_f;

    // ---- static A frags ----
    const int mt0 = wv * 4, mt1 = wv * 4 + 1, mt2 = wv * 4 + 2, mt3 = wv * 4 + 3;
    const int R0 = mt0 * 16 + lr, R1 = mt1 * 16 + lr, R2 = mt2 * 16 + lr, R3 = mt3 * 16 + lr;
    const int or0 = (R0 & 3) * 128 + (R0 >> 2);
    const int or1 = (R1 & 3) * 128 + (R1 >> 2);
    const int or2 = (R2 & 3) * 128 + (R2 >> 2);
    const int or3 = (R3 & 3) * 128 + (R3 >> 2);
    const float* p0 = Whh + (size_t)or0 * NH + lk * 4;
    const float* p1 = Whh + (size_t)or1 * NH + lk * 4;
    const float* p2 = Whh + (size_t)or2 * NH + lk * 4;
    const float* p3 = Whh + (size_t)or3 * NH + lk * 4;
    f16x8 w0_0 = mk8(p0), w0_1 = mk8(p0 + 32), w0_2 = mk8(p0 + 64), w0_3 = mk8(p0 + 96);
    f16x8 w1_0 = mk8(p1), w1_1 = mk8(p1 + 32), w1_2 = mk8(p1 + 64), w1_3 = mk8(p1 + 96);
    f16x8 w2_0 = mk8(p2), w2_1 = mk8(p2 + 32), w2_2 = mk8(p2 + 64), w2_3 = mk8(p2 + 96);
    f16x8 w3_0 = mk8(p3), w3_1 = mk8(p3 + 32), w3_2 = mk8(p3 + 64), w3_3 = mk8(p3 + 96);

    // x-weight frags, bias embedded at elem4 (k==16; live iff lk==0 via bx)
    f16x8 ax0, ax1, ax2, ax3;
#define MKAXR(DST, OR) { \
    const float* xr_ = Wih + (size_t)(OR) * NI + lk * 4; \
    DST[0] = (_Float16)xr_[0]; DST[1] = (_Float16)xr_[1]; \
    DST[2] = (_Float16)xr_[2]; DST[3] = (_Float16)xr_[3]; \
    DST[4] = (_Float16)bv[(OR)]; \
    DST[5] = (_Float16)0.f; DST[6] = (_Float16)0.f; DST[7] = (_Float16)0.f; }
    MKAXR(ax0, or0) MKAXR(ax1, or1) MKAXR(ax2, or2) MKAXR(ax3, or3)
#undef MKAXR

    const int d0 = mt0 * 4 + lk, d1 = mt1 * 4 + lk, d2 = mt2 * 4 + lk, d3 = mt3 * 4 + lk;

    // zero h buffer 0
    ((unsigned int*)hbuf0)[t] = 0u;
    ((unsigned int*)hbuf0)[t + 512] = 0u;
    float cs0 = 0.f, cs1 = 0.f, cs2 = 0.f, cs3 = 0.f;

    const int swz = (lr & 7) << 4;
    const int hro0 = (lr * 256 + 0 * 64 + lk * 16) ^ swz;
    const int hro1 = (lr * 256 + 1 * 64 + lk * 16) ^ swz;
    const int hro2 = (lr * 256 + 2 * 64 + lk * 16) ^ swz;
    const int hro3 = (lr * 256 + 3 * 64 + lk * 16) ^ swz;
#define CWB(D) (((lr * 256) + ((D) >> 5) * 64 + ((((D) & 15)) >> 2) * 16 + (((((D) & 31) >> 4) * 4 + ((D) & 3)) * 2)) ^ swz)
    const int cwb0 = CWB(d0), cwb1 = CWB(d1), cwb2 = CWB(d2), cwb3 = CWB(d3);
#undef CWB
    const int xoff = lk * 128 + lr * 8;           // bytes into xsh row
    const _Float16 onek = (lk == 0) ? (_Float16)1.0f : (_Float16)0.f;  // bx[4]
    __syncthreads();

#define CELL(J, HW) { \
    float ci_ = sigf(C##J[0]), cf_ = sigf(C##J[1]); \
    float cg_ = tanhf_(C##J[2]), co_ = sigf(C##J[3]); \
    cs##J = cf_ * cs##J + ci_ * cg_; \
    float hv_ = co_ * tanhf_(cs##J); \
    *(_Float16*)((char*)(HW) + cwb##J) = (_Float16)hv_; }

#define STEP(HR, HW, SI) { \
    const char* hrb_ = (const char*)(HR); \
    f16x8 bh0 = *(const f16x8*)(hrb_ + hro0); \
    f16x8 bh1 = *(const f16x8*)(hrb_ + hro1); \
    f16x8 bh2 = *(const f16x8*)(hrb_ + hro2); \
    f16x8 bh3 = *(const f16x8*)(hrb_ + hro3); \
    f16x4 xlo_ = *(const f16x4*)((const char*)xsh + (SI) * 512 + xoff); \
    f16x8 bx; \
    bx[0] = xlo_[0]; bx[1] = xlo_[1]; bx[2] = xlo_[2]; bx[3] = xlo_[3]; \
    bx[4] = onek; bx[5] = (_Float16)0.f; bx[6] = (_Float16)0.f; bx[7] = (_Float16)0.f; \
    f32x4 C0 = {0.f,0.f,0.f,0.f}, C1 = {0.f,0.f,0.f,0.f}; \
    f32x4 C2 = {0.f,0.f,0.f,0.f}, C3 = {0.f,0.f,0.f,0.f}; \
    C0 = MFMA(ax0, bx, C0); C1 = MFMA(ax1, bx, C1); \
    C2 = MFMA(ax2, bx, C2); C3 = MFMA(ax3, bx, C3); \
    C0 = MFMA(w0_0, bh0, C0); C1 = MFMA(w1_0, bh0, C1); \
    C2 = MFMA(w2_0, bh0, C2); C3 = MFMA(w3_0, bh0, C3); \
    C0 = MFMA(w0_1, bh1, C0); C1 = MFMA(w1_1, bh1, C1); \
    C2 = MFMA(w2_1, bh1, C2); C3 = MFMA(w3_1, bh1, C3); \
    C0 = MFMA(w0_2, bh2, C0); C1 = MFMA(w1_2, bh2, C1); \
    C2 = MFMA(w2_2, bh2, C2); C3 = MFMA(w3_2, bh2, C3); \
    C0 = MFMA(w0_3, bh3, C0); C1 = MFMA(w1_3, bh3, C1); \
    C2 = MFMA(w2_3, bh3, C2); C3 = MFMA(w3_3, bh3, C3); \
    CELL(0, HW) CELL(1, HW) CELL(2, HW) CELL(3, HW) \
    __syncthreads(); }

    for (int c = 0; c < 8; ++c) {
        // stage x chunk -> f16 LDS [si][lk][lr]
        {
            const int c0 = c * CHUNK;
            for (int i = t; i < 16 * CHUNK * 8; i += 512) {
                const int br  = i / (CHUNK * 8);
                const int rem = i - br * (CHUNK * 8);
                const int ti  = rem >> 3;
                const int dw  = rem & 7;
                const int s_  = c0 + ti;
                const int tt  = dir ? (TB - 1 - s_) : s_;
                float2 v = *(const float2*)(x + ((size_t)(b0 + br) * TB + tt) * NI + dw * 2);
                xsh[ti * 128 + (dw >> 1) * 32 + br * 2 + (dw & 1)] = packf16(v.x, v.y);
            }
        }
        __syncthreads();
        for (int si2 = 0; si2 < CHUNK / 2; ++si2) {
            STEP(hbuf0, hbuf1, si2 * 2)
            STEP(hbuf1, hbuf0, si2 * 2 + 1)
        }
    }
#undef STEP
#undef CELL

    // final states: h in hbuf0 (720 even), c in regs
    {
        const size_t base = ((size_t)(b0 + lr) * 2 + dir) * 2 * NH;
#define FIN(J) { \
        float hv_ = (float)*(const _Float16*)((const char*)hbuf0 + cwb##J); \
        st[base + d##J] = hv_; st[base + NH + d##J] = cs##J; }
        FIN(0) FIN(1) FIN(2) FIN(3)
#undef FIN
    }
}

// named-var repetition macros (arrays get scratch-demoted: R4/R6 evidence)
#define R8(F)  F(0)F(1)F(2)F(3)F(4)F(5)F(6)F(7)
#define R36_(F) F(8)F(9)F(10)F(11)F(12)F(13)F(14)F(15)F(16)F(17)F(18)F(19)F(20)F(21)F(22)F(23)F(24)F(25)F(26)F(27)F(28)F(29)F(30)F(31)F(32)F(33)F(34)F(35)
#define R36(F) R8(F) R36_(F)
#define R64(F) R36(F) F(36)F(37)F(38)F(39)F(40)F(41)F(42)F(43)F(44)F(45)F(46)F(47)F(48)F(49)F(50)F(51)F(52)F(53)F(54)F(55)F(56)F(57)F(58)F(59)F(60)F(61)F(62)F(63)

#define QD(Q,i0,i1,i2,i3) { a0 = fdot2f((Q).x, w##i0, a0); a1 = fdot2f((Q).y, w##i1, a1); \
                            a2 = fdot2f((Q).z, w##i2, a2); a3 = fdot2f((Q).w, w##i3, a3); }
#define QDU(Q,i0,i1,i2,i3) { a0 = fdot2f((Q).x, u##i0, a0); a1 = fdot2f((Q).y, u##i1, a1); \
                             a2 = fdot2f((Q).z, u##i2, a2); a3 = fdot2f((Q).w, u##i3, a3); }

// ---------------- decoder (R11: Wlin/blin/out LDS-resident) ----------------
__global__ __launch_bounds__(1024, 1)
void dec_kernel(const float* __restrict__ x,
                const float* __restrict__ Wih_f, const float* __restrict__ Whh_f, const float* __restrict__ b_f,
                const float* __restrict__ Wih_b, const float* __restrict__ Whh_b, const float* __restrict__ b_b,
                const float* __restrict__ Wlin, const float* __restrict__ blin,
                const float* __restrict__ st, float* __restrict__ out)
{
    __shared__ unsigned int hFh[NH / 2], hBh[NH / 2];
    __shared__ unsigned int inpH[NI / 2];
    __shared__ float g[1024];
    __shared__ float prt[NG];
    __shared__ float wlin_s[16 * 256];   // 16KB
    __shared__ float blin_s[16];
    __shared__ float obuf[PRED * 16];    // 6KB

    const int b    = blockIdx.x;
    const int t    = threadIdx.x;
    const int cell = t >> 9;
    const int r    = t & 511;

    const float* Wih = cell ? Wih_b : Wih_f;
    const float* Whh = cell ? Whh_b : Whh_f;
    const float* bv  = cell ? b_b   : b_f;

    for (int i = t; i < 16 * 256; i += 1024) wlin_s[i] = Wlin[i];
    if (t < 16) blin_s[t] = blin[t];

#define DW(K) unsigned int w##K;
    R64(DW)
#undef DW
#define DU(K) unsigned int u##K;
    R8(DU)
#undef DU
    {
        const float* xr = Wih + r * NI;
        const float* hr = Whh + r * NH;
#define LU(K) u##K = packf16(xr[2*(K)], xr[2*(K)+1]);
        R8(LU)
#undef LU
#define LH(K) w##K = packf16(hr[2*(K)], hr[2*(K)+1]);
        R64(LH)
#undef LH
    }
    const float bias = bv[r];

    float cc = 0.0f;
    if (t < 64) {
        const float* sh = st + ((b * 2 + 0) * 2 + 0) * NH;
        hFh[t] = packf16(sh[2 * t], sh[2 * t + 1]);
    } else if (t < 128) {
        const float* sh = st + ((b * 2 + 1) * 2 + 0) * NH;
        hBh[t - 64] = packf16(sh[2 * (t - 64)], sh[2 * (t - 64) + 1]);
    }
    if (t < NH) cc = st[((b * 2 + 0) * 2 + 1) * NH + t];
    else if (t >= 512 && t < 512 + NH) cc = st[((b * 2 + 1) * 2 + 1) * NH + (t - 512)];
    if (t < 8) {
        float2 v = ((const float2*)(x + (size_t)b * TB * NI + (TB - 1) * NI))[t];
        inpH[t] = packf16(v.x, v.y);
    }
    __syncthreads();

    for (int s = 0; s < PRED; ++s) {
        float a0 = bias, a1 = 0.f, a2 = 0.f, a3 = 0.f;
        uint4 q;
        {
            const uint4* xv = (const uint4*)inpH;
            q = xv[0]; QDU(q, 0, 1, 2, 3)
            q = xv[1]; QDU(q, 4, 5, 6, 7)
        }
        const uint4* hv = cell ? (const uint4*)hBh : (const uint4*)hFh;
        q = hv[0];  QD(q, 0, 1, 2, 3)
        q = hv[1];  QD(q, 4, 5, 6, 7)
        q = hv[2];  QD(q, 8, 9, 10, 11)
        q = hv[3];  QD(q, 12, 13, 14, 15)
        q = hv[4];  QD(q, 16, 17, 18, 19)
        q = hv[5];  QD(q, 20, 21, 22, 23)
        q = hv[6];  QD(q, 24, 25, 26, 27)
        q = hv[7];  QD(q, 28, 29, 30, 31)
        q = hv[8];  QD(q, 32, 33, 34, 35)
        q = hv[9];  QD(q, 36, 37, 38, 39)
        q = hv[10]; QD(q, 40, 41, 42, 43)
        q = hv[11]; QD(q, 44, 45, 46, 47)
        q = hv[12]; QD(q, 48, 49, 50, 51)
        q = hv[13]; QD(q, 52, 53, 54, 55)
        q = hv[14]; QD(q, 56, 57, 58, 59)
        q = hv[15]; QD(q, 60, 61, 62, 63)
        g[t] = (a0 + a1) + (a2 + a3);
        __syncthreads();
        if ((t < NH) || (t >= 512 && t < 512 + NH)) {
            float gi = g[t], gf = g[t + NH], gg = g[t + 2 * NH], go = g[t + 3 * NH];
            cc = sigf(gf) * cc + sigf(gi) * tanhf_(gg);
            float h = sigf(go) * tanhf_(cc);
            if (t < NH) ((_Float16*)hFh)[t] = (_Float16)h;
            else        ((_Float16*)hBh)[t - 512] = (_Float16)h;
        }
        __syncthreads();
        if (t < NG) {
            const int j = t >> 5, ch = t & 31;
            const unsigned int* hsrc = (ch < 16) ? (hFh + ch * 4) : (hBh + (ch - 16) * 4);
            const float* wl = wlin_s + j * 256 + ch * 8;
            float2 v0 = unpackf16(hsrc[0]);
            float2 v1 = unpackf16(hsrc[1]);
            float2 v2 = unpackf16(hsrc[2]);
            float2 v3 = unpackf16(hsrc[3]);
            prt[t] = v0.x * wl[0] + v0.y * wl[1] + v1.x * wl[2] + v1.y * wl[3]
                   + v2.x * wl[4] + v2.y * wl[5] + v3.x * wl[6] + v3.y * wl[7];
        }
        __syncthreads();
        if (t < NI) {
            float o = blin_s[t];
#pragma unroll
            for (int c2 = 0; c2 < 32; ++c2) o += prt[t * 32 + c2];
            obuf[s * NI + t] = o;
            ((_Float16*)inpH)[t] = (_Float16)o;
        }
        __syncthreads();
    }

    {
        float4* dst = (float4*)(out + (size_t)b * PRED * NI);
        const float4* src = (const float4*)obuf;
        for (int i = t; i < PRED * NI / 4; i += 1024) dst[i] = src[i];
    }
}

extern "C" void kernel_launch(void* const* d_in, const int* in_sizes, int n_in,
                              void* d_out, int out_size, void* d_ws, size_t ws_size,
                              hipStream_t stream)
{
    const float* x      = (const float*)d_in[0];
    const float* eWih_f = (const float*)d_in[1];
    const float* eWhh_f = (const float*)d_in[2];
    const float* eb_f   = (const float*)d_in[3];
    const float* eWih_b = (const float*)d_in[4];
    const float* eWhh_b = (const float*)d_in[5];
    const float* eb_b   = (const float*)d_in[6];
    const float* dWih_f = (const float*)d_in[7];
    const float* dWhh_f = (const float*)d_in[8];
    const float* db_f   = (const float*)d_in[9];
    const float* dWih_b = (const float*)d_in[10];
    const float* dWhh_b = (const float*)d_in[11];
    const float* db_b   = (const float*)d_in[12];
    const float* Wlin   = (const float*)d_in[13];
    const float* blin   = (const float*)d_in[14];

    float* st = (float*)d_ws;  // 256*2*2*128 f32 encoder final states

    enc_kernel<<<32, 512, 0, stream>>>(x, eWih_f, eWhh_f, eb_f, eWih_b, eWhh_b, eb_b, st);
    dec_kernel<<<256, 1024, 0, stream>>>(x, dWih_f, dWhh_f, db_f, dWih_b, dWhh_b, db_b,
                                         Wlin, blin, st, (float*)d_out);
}